// Round 1
// baseline (183.916 us; speedup 1.0000x reference)
//
#include <hip/hip_runtime.h>
#include <math.h>

// Problem constants (fixed by the reference setup_inputs)
#define NIMG   64
#define CDIM   64
#define HWPX   4096
#define KCL    128
#define TL     32                // pixels per chunk
#define SHIFT  10.0f             // softmax shift folded into bias
#define RSQRT128 0.08838834764831845f

// LDS strides in shorts (multiples of 8 so b128 stays 16B-aligned)
#define XP_S 72    // xp planes [32 p][64 c]
#define XC_S 40    // xc plane  [64 c][32 p]
#define PH_S 40    // ph plane  [128 k][32 p]

typedef __attribute__((ext_vector_type(8))) short short8; // 8 bf16
typedef __attribute__((ext_vector_type(4))) float f32x4;  // MFMA C/D

#define MFMA(a, b, c) __builtin_amdgcn_mfma_f32_16x16x32_bf16((a), (b), (c), 0, 0, 0)

// truncation split for mm1 (hi exact-prefix + lo correction): 3-term MFMA
__device__ __forceinline__ void tsplit(float f, short& hs, short& ls) {
    unsigned u = __builtin_bit_cast(unsigned, f);
    hs = (short)(u >> 16);
    float hf = __builtin_bit_cast(float, u & 0xffff0000u);
    ls = (short)(__builtin_bit_cast(unsigned, f - hf) >> 16);
}
// round-to-nearest-even bf16 for mm2's single-plane operands
__device__ __forceinline__ short f2bf(float f) {
    unsigned u = __builtin_bit_cast(unsigned, f);
    return (short)((u + 0x7fffu + ((u >> 16) & 1u)) >> 16);
}

// ---------------------------------------------------------------------------
// Kernel 1: raw-x planes -> mm1 (W@X, 3-term split) -> in-register softmax
// -> mm2 (P'@X^T, single bf16 planes -- error bounded ~4e-6 on output
// because the VLAD residual is dominated by asum*centroid).
// LESSONS (measured): (256,3)/spill r3+r9; __threadfence 3x r6; 512-thr
// blocks r5.
// R11: 512 blocks (2/CU) was latency/barrier-bound: Occupancy 16.7%,
// MfmaUtil 13%, VALU 37%, HBM 13% -- nothing saturated, 48 barriers/block
// with only 1 other block/CU to cover each drain. -> NP=16: 1024 blocks =
// 4 blocks/CU exact (LDS 26.1KB*4 = 104KB < 160KB; VGPR 84 <= 128 cap from
// launch_bounds(256,4)). Workspace-tiered fallback to NP=8 if ws too small.
// ---------------------------------------------------------------------------
template <int NP>
__global__ __launch_bounds__(256, 4)
void netvlad_main(const float* __restrict__ x,       // [N][C][HW]
                  const float* __restrict__ conv_w,  // [K][C]
                  const float* __restrict__ conv_b,  // [K]
                  float* __restrict__ vout,          // partials or atomic acc
                  float* __restrict__ asout,
                  int use_atomic)
{
    constexpr int PIXPART = HWPX / NP;   // pixels per block
    constexpr int NCHUNK  = PIXPART / TL;

    __shared__ __align__(16) short xp_hi[TL * XP_S], xp_lo[TL * XP_S]; // 9 KB
    __shared__ __align__(16) short xc[CDIM * XC_S];                    // 5 KB
    __shared__ __align__(16) short ph[KCL * PH_S];                     // 10 KB
    __shared__ float redA[4 * 33];    // ssq partials [wave][p], stride 33
    __shared__ float sumP[4 * TL];    // exp-sum partials [wave][p]

    const int t   = threadIdx.x;
    const int w   = t >> 6;             // wave 0..3
    const int l   = t & 63;
    const int l15 = l & 15, l4 = l >> 4;
    const int n    = blockIdx.x / NP;
    const int part = blockIdx.x - n * NP;
    const int p_s  = t & 31;            // staging pixel
    const int sg   = t >> 5;            // staging c-group (8 c's)

    // ---- W fragments in registers (once): A[m=k][kdim=c], 3-term split ----
    short8 wh[2][2], wl[2][2];
    #pragma unroll
    for (int kt = 0; kt < 2; ++kt) {
        const int krow = (2 * w + kt) * 16 + l15;
        #pragma unroll
        for (int ks = 0; ks < 2; ++ks) {
            const float4* wp = (const float4*)(conv_w + krow * CDIM + ks * 32 + l4 * 8);
            float4 wa = wp[0], wb = wp[1];
            float wv[8] = {wa.x, wa.y, wa.z, wa.w, wb.x, wb.y, wb.z, wb.w};
            #pragma unroll
            for (int j = 0; j < 8; ++j) {
                short hs, ls; tsplit(wv[j], hs, ls);
                wh[kt][ks][j] = hs; wl[kt][ks][j] = ls;
            }
        }
    }
    // bias per D-row (k = (2w+kt)*16 + l4*4 + i), pre-shifted
    float cbr[2][4];
    #pragma unroll
    for (int kt = 0; kt < 2; ++kt)
        #pragma unroll
        for (int i = 0; i < 4; ++i)
            cbr[kt][i] = conv_b[(2 * w + kt) * 16 + l4 * 4 + i] - SHIFT;

    f32x4 acc2[2][4];                   // V tiles [kt][ct]
    #pragma unroll
    for (int a = 0; a < 2; ++a)
        #pragma unroll
        for (int b = 0; b < 4; ++b) acc2[a][b] = (f32x4)0.0f;
    float asr[2][4];                    // asum partials per D-row
    #pragma unroll
    for (int a = 0; a < 2; ++a)
        #pragma unroll
        for (int i = 0; i < 4; ++i) asr[a][i] = 0.f;

    const float* xbase = x + (size_t)n * CDIM * HWPX + part * PIXPART;

    // preload chunk 0
    float xv[8];
    #pragma unroll
    for (int j = 0; j < 8; ++j)
        xv[j] = xbase[(sg * 8 + j) * HWPX + p_s];

    for (int ch = 0; ch < NCHUNK; ++ch) {
        // ---- stage: ssq partial + x planes --------------------------------
        float ssq = 0.f;
        #pragma unroll
        for (int j = 0; j < 8; ++j) ssq += xv[j] * xv[j];
        ssq += __shfl_xor(ssq, 32);              // combine the wave's 2 sg's
        if (l < 32) redA[w * 33 + p_s] = ssq;

        short8 vh, vl;
        #pragma unroll
        for (int j = 0; j < 8; ++j) {
            short hs, ls; tsplit(xv[j], hs, ls);
            vh[j] = hs; vl[j] = ls;
            xc[(sg * 8 + j) * XC_S + p_s] = f2bf(xv[j]);   // mm2 plane (RNE)
        }
        *(short8*)&xp_hi[p_s * XP_S + sg * 8] = vh;
        *(short8*)&xp_lo[p_s * XP_S + sg * 8] = vl;
        __syncthreads();                                  // bar 1: stage done

        // prefetch next chunk while mm1/softmax/mm2 run
        if (ch + 1 < NCHUNK) {
            #pragma unroll
            for (int j = 0; j < 8; ++j)
                xv[j] = xbase[(sg * 8 + j) * HWPX + (ch + 1) * TL + p_s];
        }

        // ---- mm1: a1[kt][pt] = W @ Xraw  (3-term split) -------------------
        f32x4 a1[2][2];
        #pragma unroll
        for (int a = 0; a < 2; ++a)
            #pragma unroll
            for (int b = 0; b < 2; ++b) a1[a][b] = (f32x4)0.0f;
        #pragma unroll
        for (int ks = 0; ks < 2; ++ks) {
            #pragma unroll
            for (int pt = 0; pt < 2; ++pt) {
                short8 bh = *(short8*)&xp_hi[(pt * 16 + l15) * XP_S + ks * 32 + l4 * 8];
                short8 bl = *(short8*)&xp_lo[(pt * 16 + l15) * XP_S + ks * 32 + l4 * 8];
                #pragma unroll
                for (int kt = 0; kt < 2; ++kt) {
                    a1[kt][pt] = MFMA(wh[kt][ks], bh, a1[kt][pt]);
                    a1[kt][pt] = MFMA(wh[kt][ks], bl, a1[kt][pt]);
                    a1[kt][pt] = MFMA(wl[kt][ks], bh, a1[kt][pt]);
                }
            }
        }

        // ---- per-column 1/||x||: sum the 4 per-wave ssq partials ----------
        float rn[2];
        #pragma unroll
        for (int pt = 0; pt < 2; ++pt) {
            const int col = pt * 16 + l15;
            float s0 = redA[col] + redA[33 + col];
            float s1 = redA[2 * 33 + col] + redA[3 * 33 + col];
            rn[pt] = 1.0f / fmaxf(sqrtf(s0 + s1), 1e-12f);
        }

        // ---- in-register softmax over k (no max pass; bias pre-shifted) ---
        float e[2][2][4], sp[2] = {0.f, 0.f};
        #pragma unroll
        for (int kt = 0; kt < 2; ++kt)
            #pragma unroll
            for (int pt = 0; pt < 2; ++pt)
                #pragma unroll
                for (int i = 0; i < 4; ++i) {
                    float ev = __expf(fmaf(a1[kt][pt][i], rn[pt], cbr[kt][i]));
                    e[kt][pt][i] = ev;
                    sp[pt] += ev;
                }
        #pragma unroll
        for (int pt = 0; pt < 2; ++pt) {
            sp[pt] += __shfl_xor(sp[pt], 16);
            sp[pt] += __shfl_xor(sp[pt], 32);     // wave-sum over its 32 k's
        }
        if (l4 == 0) {
            sumP[w * TL + l15]      = sp[0];
            sumP[w * TL + 16 + l15] = sp[1];
        }
        __syncthreads();                                  // bar 2: sumP done

        float rden[2], rdn2[2];
        #pragma unroll
        for (int pt = 0; pt < 2; ++pt) {
            const int col = pt * 16 + l15;
            float den = sumP[col] + sumP[TL + col] + sumP[2 * TL + col] + sumP[3 * TL + col];
            rden[pt] = 1.0f / den;
            rdn2[pt] = rden[pt] * rn[pt];          // fold 1/||x|| into P'
        }

        // ---- P' = P * rn -> single bf16 plane (wave's own 32 ph rows) -----
        #pragma unroll
        for (int kt = 0; kt < 2; ++kt)
            #pragma unroll
            for (int i = 0; i < 4; ++i) {
                const int row = (2 * w + kt) * 16 + l4 * 4 + i;
                #pragma unroll
                for (int pt = 0; pt < 2; ++pt) {
                    float ev = e[kt][pt][i];
                    asr[kt][i] = fmaf(ev, rden[pt], asr[kt][i]);
                    ph[row * PH_S + pt * 16 + l15] = f2bf(ev * rdn2[pt]);
                }
            }
        // no barrier: mm2 reads only the ph rows this wave just wrote
        // (intra-wave LDS ordering is guaranteed).

        // ---- mm2: V[k][c] += P' @ Xraw^T (single-plane bf16) --------------
        {
            short8 xh2[4];
            #pragma unroll
            for (int ct = 0; ct < 4; ++ct)
                xh2[ct] = *(short8*)&xc[(ct * 16 + l15) * XC_S + l4 * 8];
            #pragma unroll
            for (int kt = 0; kt < 2; ++kt) {
                short8 ah = *(short8*)&ph[((2 * w + kt) * 16 + l15) * PH_S + l4 * 8];
                #pragma unroll
                for (int ct = 0; ct < 4; ++ct)
                    acc2[kt][ct] = MFMA(ah, xh2[ct], acc2[kt][ct]);
            }
        }
        __syncthreads();                                  // bar 3: chunk end
    }

    // ---- V write (coalesced: lanes l15 -> consecutive c) ------------------
    float* vg = use_atomic ? vout + (size_t)n * KCL * CDIM
                           : vout + (size_t)blockIdx.x * KCL * CDIM;
    #pragma unroll
    for (int kt = 0; kt < 2; ++kt)
        #pragma unroll
        for (int ct = 0; ct < 4; ++ct)
            #pragma unroll
            for (int i = 0; i < 4; ++i) {
                const int row = (2 * w + kt) * 16 + l4 * 4 + i;
                const int col = ct * 16 + l15;
                if (use_atomic) atomicAdd(&vg[row * CDIM + col], acc2[kt][ct][i]);
                else            vg[row * CDIM + col] = acc2[kt][ct][i];
            }

    // ---- asum: reduce over l15 lanes, lane0-of-16 writes ------------------
    #pragma unroll
    for (int kt = 0; kt < 2; ++kt)
        #pragma unroll
        for (int i = 0; i < 4; ++i) {
            float v = asr[kt][i];
            v += __shfl_xor(v, 1); v += __shfl_xor(v, 2);
            v += __shfl_xor(v, 4); v += __shfl_xor(v, 8);
            if (l15 == 0) {
                const int row = (2 * w + kt) * 16 + l4 * 4 + i;
                if (use_atomic) atomicAdd(&asout[n * KCL + row], v);
                else            asout[blockIdx.x * KCL + row] = v;
            }
        }
}

// ---------------------------------------------------------------------------
// Kernel 2: sum partials; vlad = V - asum*cent; intra-norm; global norm.
// After intra-norm every row has unit L2 norm -> global denom = sqrt(128).
// grid = NIMG*8 blocks x 256 threads; thread -> (k, 4 c's). Fully parallel.
// ---------------------------------------------------------------------------
__global__ __launch_bounds__(256)
void netvlad_finalize(const float* __restrict__ vpart,   // [N][nparts][K][C]
                      const float* __restrict__ aspart,  // [N][nparts][K]
                      const float* __restrict__ cent,    // [K][C]
                      float* __restrict__ out,           // [N][K*C]
                      int nparts)
{
    const int t = threadIdx.x;
    const int n  = blockIdx.x >> 3;
    const int kg = blockIdx.x & 7;
    const int k  = kg * 16 + (t >> 4);
    const int c0 = (t & 15) * 4;

    float vsum[4] = {0.f, 0.f, 0.f, 0.f};
    float av = 0.f;
    for (int pt = 0; pt < nparts; ++pt) {
        const float* vg = vpart + (((size_t)n * nparts + pt) * KCL + k) * CDIM + c0;
        float4 a = *(const float4*)vg;
        vsum[0] += a.x; vsum[1] += a.y; vsum[2] += a.z; vsum[3] += a.w;
        av += aspart[(n * nparts + pt) * KCL + k];
    }

    float4 cq = *(const float4*)(cent + k * CDIM + c0);
    float cc[4] = {cq.x, cq.y, cq.z, cq.w};
    float ss = 0.f;
    #pragma unroll
    for (int j = 0; j < 4; ++j) {
        vsum[j] -= av * cc[j];
        ss += vsum[j] * vsum[j];
    }
    // row sumsq over the 16 lanes covering this k
    ss += __shfl_xor(ss, 1); ss += __shfl_xor(ss, 2);
    ss += __shfl_xor(ss, 4); ss += __shfl_xor(ss, 8);
    const float s = (1.0f / fmaxf(sqrtf(ss), 1e-12f)) * RSQRT128;

    float4 o;
    o.x = vsum[0] * s; o.y = vsum[1] * s; o.z = vsum[2] * s; o.w = vsum[3] * s;
    *(float4*)(out + (size_t)n * KCL * CDIM + k * CDIM + c0) = o;
}

// ---------------------------------------------------------------------------
extern "C" void kernel_launch(void* const* d_in, const int* in_sizes, int n_in,
                              void* d_out, int out_size, void* d_ws, size_t ws_size,
                              hipStream_t stream) {
    const float* x     = (const float*)d_in[0];   // [64,64,64,64]
    const float* cent  = (const float*)d_in[1];   // [128,64]
    const float* convw = (const float*)d_in[2];   // [128,64]
    const float* convb = (const float*)d_in[3];   // [128]
    float* out = (float*)d_out;

    const size_t need16 = (size_t)NIMG * 16 * (KCL * CDIM + KCL) * sizeof(float);
    const size_t need8  = (size_t)NIMG * 8  * (KCL * CDIM + KCL) * sizeof(float);

    if (ws_size >= need16) {
        // R11 primary path: 1024 blocks = 4/CU exact.
        float* vws  = (float*)d_ws;                               // [N][16][K][C]
        float* asws = vws + (size_t)NIMG * 16 * KCL * CDIM;       // [N][16][K]
        netvlad_main<16><<<dim3(NIMG * 16), dim3(256), 0, stream>>>(
            x, convw, convb, vws, asws, 0);
        netvlad_finalize<<<dim3(NIMG * 8), dim3(256), 0, stream>>>(
            vws, asws, cent, out, 16);
    } else if (ws_size >= need8) {
        float* vws  = (float*)d_ws;                               // [N][8][K][C]
        float* asws = vws + (size_t)NIMG * 8 * KCL * CDIM;        // [N][8][K]
        netvlad_main<8><<<dim3(NIMG * 8), dim3(256), 0, stream>>>(
            x, convw, convb, vws, asws, 0);
        netvlad_finalize<<<dim3(NIMG * 8), dim3(256), 0, stream>>>(
            vws, asws, cent, out, 8);
    } else {
        float* vws  = (float*)d_ws;                               // [N][K][C]
        float* asws = vws + (size_t)NIMG * KCL * CDIM;            // [N][K]
        const size_t zb = (size_t)NIMG * (KCL * CDIM + KCL) * sizeof(float);
        hipMemsetAsync(d_ws, 0, zb, stream);
        netvlad_main<8><<<dim3(NIMG * 8), dim3(256), 0, stream>>>(
            x, convw, convb, vws, asws, 1);
        netvlad_finalize<<<dim3(NIMG * 8), dim3(256), 0, stream>>>(
            vws, asws, cent, out, 1);
    }
}

// Round 2
// 131.268 us; speedup vs baseline: 1.4011x; 1.4011x over previous
//
#include <hip/hip_runtime.h>
#include <math.h>

// Problem constants (fixed by the reference setup_inputs)
#define NIMG   64
#define CDIM   64
#define HWPX   4096
#define KCL    128
#define TL     32                // pixels per chunk
#define SHIFT  10.0f             // softmax shift folded into bias
#define RSQRT128 0.08838834764831845f

// LDS strides in shorts (multiples of 8 so b128 stays 16B-aligned)
#define XP_S 72    // xp planes [32 p][64 c]
#define XC_S 40    // xc plane  [64 c][32 p]
#define PH_S 40    // ph plane  [128 k][32 p]

typedef __attribute__((ext_vector_type(8))) short short8; // 8 bf16
typedef __attribute__((ext_vector_type(4))) float f32x4;  // MFMA C/D

#define MFMA(a, b, c) __builtin_amdgcn_mfma_f32_16x16x32_bf16((a), (b), (c), 0, 0, 0)

// truncation split for mm1 (hi exact-prefix + lo correction): 3-term MFMA
__device__ __forceinline__ void tsplit(float f, short& hs, short& ls) {
    unsigned u = __builtin_bit_cast(unsigned, f);
    hs = (short)(u >> 16);
    float hf = __builtin_bit_cast(float, u & 0xffff0000u);
    ls = (short)(__builtin_bit_cast(unsigned, f - hf) >> 16);
}
// round-to-nearest-even bf16 for mm2's single-plane operands
__device__ __forceinline__ short f2bf(float f) {
    unsigned u = __builtin_bit_cast(unsigned, f);
    return (short)((u + 0x7fffu + ((u >> 16) & 1u)) >> 16);
}

// ---------------------------------------------------------------------------
// Kernel 1: raw-x planes -> mm1 (W@X, 3-term split) -> in-register softmax
// -> mm2 (P'@X^T, single bf16 planes -- error bounded ~4e-6 on output
// because the VLAD residual is dominated by asum*centroid).
// LESSONS (measured): (256,3)/spill r3+r9; __threadfence 3x r6; 512-thr
// blocks r5.
// R11 (FAILED): launch_bounds(256,4) clamped VGPR 84->64 -> scratch spills
// (+~55MB HBM traffic), MfmaUtil 6.6%, 2.1x slower. The occupancy change
// never needed it: 84 VGPR already allows 4 waves/SIMD (steps at 64/128/256)
// and LDS 26.1KB allows 6 blocks/CU. R0 was GRID-limited (512 blocks = 2/CU).
// R12: NP=16 (1024 blocks = 4/CU) with the ORIGINAL launch_bounds(256,2).
// ---------------------------------------------------------------------------
template <int NP>
__global__ __launch_bounds__(256, 2)
void netvlad_main(const float* __restrict__ x,       // [N][C][HW]
                  const float* __restrict__ conv_w,  // [K][C]
                  const float* __restrict__ conv_b,  // [K]
                  float* __restrict__ vout,          // partials or atomic acc
                  float* __restrict__ asout,
                  int use_atomic)
{
    constexpr int PIXPART = HWPX / NP;   // pixels per block
    constexpr int NCHUNK  = PIXPART / TL;

    __shared__ __align__(16) short xp_hi[TL * XP_S], xp_lo[TL * XP_S]; // 9 KB
    __shared__ __align__(16) short xc[CDIM * XC_S];                    // 5 KB
    __shared__ __align__(16) short ph[KCL * PH_S];                     // 10 KB
    __shared__ float redA[4 * 33];    // ssq partials [wave][p], stride 33
    __shared__ float sumP[4 * TL];    // exp-sum partials [wave][p]

    const int t   = threadIdx.x;
    const int w   = t >> 6;             // wave 0..3
    const int l   = t & 63;
    const int l15 = l & 15, l4 = l >> 4;
    const int n    = blockIdx.x / NP;
    const int part = blockIdx.x - n * NP;
    const int p_s  = t & 31;            // staging pixel
    const int sg   = t >> 5;            // staging c-group (8 c's)

    // ---- W fragments in registers (once): A[m=k][kdim=c], 3-term split ----
    short8 wh[2][2], wl[2][2];
    #pragma unroll
    for (int kt = 0; kt < 2; ++kt) {
        const int krow = (2 * w + kt) * 16 + l15;
        #pragma unroll
        for (int ks = 0; ks < 2; ++ks) {
            const float4* wp = (const float4*)(conv_w + krow * CDIM + ks * 32 + l4 * 8);
            float4 wa = wp[0], wb = wp[1];
            float wv[8] = {wa.x, wa.y, wa.z, wa.w, wb.x, wb.y, wb.z, wb.w};
            #pragma unroll
            for (int j = 0; j < 8; ++j) {
                short hs, ls; tsplit(wv[j], hs, ls);
                wh[kt][ks][j] = hs; wl[kt][ks][j] = ls;
            }
        }
    }
    // bias per D-row (k = (2w+kt)*16 + l4*4 + i), pre-shifted
    float cbr[2][4];
    #pragma unroll
    for (int kt = 0; kt < 2; ++kt)
        #pragma unroll
        for (int i = 0; i < 4; ++i)
            cbr[kt][i] = conv_b[(2 * w + kt) * 16 + l4 * 4 + i] - SHIFT;

    f32x4 acc2[2][4];                   // V tiles [kt][ct]
    #pragma unroll
    for (int a = 0; a < 2; ++a)
        #pragma unroll
        for (int b = 0; b < 4; ++b) acc2[a][b] = (f32x4)0.0f;
    float asr[2][4];                    // asum partials per D-row
    #pragma unroll
    for (int a = 0; a < 2; ++a)
        #pragma unroll
        for (int i = 0; i < 4; ++i) asr[a][i] = 0.f;

    const float* xbase = x + (size_t)n * CDIM * HWPX + part * PIXPART;

    // preload chunk 0
    float xv[8];
    #pragma unroll
    for (int j = 0; j < 8; ++j)
        xv[j] = xbase[(sg * 8 + j) * HWPX + p_s];

    for (int ch = 0; ch < NCHUNK; ++ch) {
        // ---- stage: ssq partial + x planes --------------------------------
        float ssq = 0.f;
        #pragma unroll
        for (int j = 0; j < 8; ++j) ssq += xv[j] * xv[j];
        ssq += __shfl_xor(ssq, 32);              // combine the wave's 2 sg's
        if (l < 32) redA[w * 33 + p_s] = ssq;

        short8 vh, vl;
        #pragma unroll
        for (int j = 0; j < 8; ++j) {
            short hs, ls; tsplit(xv[j], hs, ls);
            vh[j] = hs; vl[j] = ls;
            xc[(sg * 8 + j) * XC_S + p_s] = f2bf(xv[j]);   // mm2 plane (RNE)
        }
        *(short8*)&xp_hi[p_s * XP_S + sg * 8] = vh;
        *(short8*)&xp_lo[p_s * XP_S + sg * 8] = vl;
        __syncthreads();                                  // bar 1: stage done

        // prefetch next chunk while mm1/softmax/mm2 run
        if (ch + 1 < NCHUNK) {
            #pragma unroll
            for (int j = 0; j < 8; ++j)
                xv[j] = xbase[(sg * 8 + j) * HWPX + (ch + 1) * TL + p_s];
        }

        // ---- mm1: a1[kt][pt] = W @ Xraw  (3-term split) -------------------
        f32x4 a1[2][2];
        #pragma unroll
        for (int a = 0; a < 2; ++a)
            #pragma unroll
            for (int b = 0; b < 2; ++b) a1[a][b] = (f32x4)0.0f;
        #pragma unroll
        for (int ks = 0; ks < 2; ++ks) {
            #pragma unroll
            for (int pt = 0; pt < 2; ++pt) {
                short8 bh = *(short8*)&xp_hi[(pt * 16 + l15) * XP_S + ks * 32 + l4 * 8];
                short8 bl = *(short8*)&xp_lo[(pt * 16 + l15) * XP_S + ks * 32 + l4 * 8];
                #pragma unroll
                for (int kt = 0; kt < 2; ++kt) {
                    a1[kt][pt] = MFMA(wh[kt][ks], bh, a1[kt][pt]);
                    a1[kt][pt] = MFMA(wh[kt][ks], bl, a1[kt][pt]);
                    a1[kt][pt] = MFMA(wl[kt][ks], bh, a1[kt][pt]);
                }
            }
        }

        // ---- per-column 1/||x||: sum the 4 per-wave ssq partials ----------
        float rn[2];
        #pragma unroll
        for (int pt = 0; pt < 2; ++pt) {
            const int col = pt * 16 + l15;
            float s0 = redA[col] + redA[33 + col];
            float s1 = redA[2 * 33 + col] + redA[3 * 33 + col];
            rn[pt] = 1.0f / fmaxf(sqrtf(s0 + s1), 1e-12f);
        }

        // ---- in-register softmax over k (no max pass; bias pre-shifted) ---
        float e[2][2][4], sp[2] = {0.f, 0.f};
        #pragma unroll
        for (int kt = 0; kt < 2; ++kt)
            #pragma unroll
            for (int pt = 0; pt < 2; ++pt)
                #pragma unroll
                for (int i = 0; i < 4; ++i) {
                    float ev = __expf(fmaf(a1[kt][pt][i], rn[pt], cbr[kt][i]));
                    e[kt][pt][i] = ev;
                    sp[pt] += ev;
                }
        #pragma unroll
        for (int pt = 0; pt < 2; ++pt) {
            sp[pt] += __shfl_xor(sp[pt], 16);
            sp[pt] += __shfl_xor(sp[pt], 32);     // wave-sum over its 32 k's
        }
        if (l4 == 0) {
            sumP[w * TL + l15]      = sp[0];
            sumP[w * TL + 16 + l15] = sp[1];
        }
        __syncthreads();                                  // bar 2: sumP done

        float rden[2], rdn2[2];
        #pragma unroll
        for (int pt = 0; pt < 2; ++pt) {
            const int col = pt * 16 + l15;
            float den = sumP[col] + sumP[TL + col] + sumP[2 * TL + col] + sumP[3 * TL + col];
            rden[pt] = 1.0f / den;
            rdn2[pt] = rden[pt] * rn[pt];          // fold 1/||x|| into P'
        }

        // ---- P' = P * rn -> single bf16 plane (wave's own 32 ph rows) -----
        #pragma unroll
        for (int kt = 0; kt < 2; ++kt)
            #pragma unroll
            for (int i = 0; i < 4; ++i) {
                const int row = (2 * w + kt) * 16 + l4 * 4 + i;
                #pragma unroll
                for (int pt = 0; pt < 2; ++pt) {
                    float ev = e[kt][pt][i];
                    asr[kt][i] = fmaf(ev, rden[pt], asr[kt][i]);
                    ph[row * PH_S + pt * 16 + l15] = f2bf(ev * rdn2[pt]);
                }
            }
        // no barrier: mm2 reads only the ph rows this wave just wrote
        // (intra-wave LDS ordering is guaranteed).

        // ---- mm2: V[k][c] += P' @ Xraw^T (single-plane bf16) --------------
        {
            short8 xh2[4];
            #pragma unroll
            for (int ct = 0; ct < 4; ++ct)
                xh2[ct] = *(short8*)&xc[(ct * 16 + l15) * XC_S + l4 * 8];
            #pragma unroll
            for (int kt = 0; kt < 2; ++kt) {
                short8 ah = *(short8*)&ph[((2 * w + kt) * 16 + l15) * PH_S + l4 * 8];
                #pragma unroll
                for (int ct = 0; ct < 4; ++ct)
                    acc2[kt][ct] = MFMA(ah, xh2[ct], acc2[kt][ct]);
            }
        }
        __syncthreads();                                  // bar 3: chunk end
    }

    // ---- V write (coalesced: lanes l15 -> consecutive c) ------------------
    float* vg = use_atomic ? vout + (size_t)n * KCL * CDIM
                           : vout + (size_t)blockIdx.x * KCL * CDIM;
    #pragma unroll
    for (int kt = 0; kt < 2; ++kt)
        #pragma unroll
        for (int ct = 0; ct < 4; ++ct)
            #pragma unroll
            for (int i = 0; i < 4; ++i) {
                const int row = (2 * w + kt) * 16 + l4 * 4 + i;
                const int col = ct * 16 + l15;
                if (use_atomic) atomicAdd(&vg[row * CDIM + col], acc2[kt][ct][i]);
                else            vg[row * CDIM + col] = acc2[kt][ct][i];
            }

    // ---- asum: reduce over l15 lanes, lane0-of-16 writes ------------------
    #pragma unroll
    for (int kt = 0; kt < 2; ++kt)
        #pragma unroll
        for (int i = 0; i < 4; ++i) {
            float v = asr[kt][i];
            v += __shfl_xor(v, 1); v += __shfl_xor(v, 2);
            v += __shfl_xor(v, 4); v += __shfl_xor(v, 8);
            if (l15 == 0) {
                const int row = (2 * w + kt) * 16 + l4 * 4 + i;
                if (use_atomic) atomicAdd(&asout[n * KCL + row], v);
                else            asout[blockIdx.x * KCL + row] = v;
            }
        }
}

// ---------------------------------------------------------------------------
// Kernel 2: sum partials; vlad = V - asum*cent; intra-norm; global norm.
// After intra-norm every row has unit L2 norm -> global denom = sqrt(128).
// grid = NIMG*8 blocks x 256 threads; thread -> (k, 4 c's). Fully parallel.
// ---------------------------------------------------------------------------
__global__ __launch_bounds__(256)
void netvlad_finalize(const float* __restrict__ vpart,   // [N][nparts][K][C]
                      const float* __restrict__ aspart,  // [N][nparts][K]
                      const float* __restrict__ cent,    // [K][C]
                      float* __restrict__ out,           // [N][K*C]
                      int nparts)
{
    const int t = threadIdx.x;
    const int n  = blockIdx.x >> 3;
    const int kg = blockIdx.x & 7;
    const int k  = kg * 16 + (t >> 4);
    const int c0 = (t & 15) * 4;

    float vsum[4] = {0.f, 0.f, 0.f, 0.f};
    float av = 0.f;
    for (int pt = 0; pt < nparts; ++pt) {
        const float* vg = vpart + (((size_t)n * nparts + pt) * KCL + k) * CDIM + c0;
        float4 a = *(const float4*)vg;
        vsum[0] += a.x; vsum[1] += a.y; vsum[2] += a.z; vsum[3] += a.w;
        av += aspart[(n * nparts + pt) * KCL + k];
    }

    float4 cq = *(const float4*)(cent + k * CDIM + c0);
    float cc[4] = {cq.x, cq.y, cq.z, cq.w};
    float ss = 0.f;
    #pragma unroll
    for (int j = 0; j < 4; ++j) {
        vsum[j] -= av * cc[j];
        ss += vsum[j] * vsum[j];
    }
    // row sumsq over the 16 lanes covering this k
    ss += __shfl_xor(ss, 1); ss += __shfl_xor(ss, 2);
    ss += __shfl_xor(ss, 4); ss += __shfl_xor(ss, 8);
    const float s = (1.0f / fmaxf(sqrtf(ss), 1e-12f)) * RSQRT128;

    float4 o;
    o.x = vsum[0] * s; o.y = vsum[1] * s; o.z = vsum[2] * s; o.w = vsum[3] * s;
    *(float4*)(out + (size_t)n * KCL * CDIM + k * CDIM + c0) = o;
}

// ---------------------------------------------------------------------------
extern "C" void kernel_launch(void* const* d_in, const int* in_sizes, int n_in,
                              void* d_out, int out_size, void* d_ws, size_t ws_size,
                              hipStream_t stream) {
    const float* x     = (const float*)d_in[0];   // [64,64,64,64]
    const float* cent  = (const float*)d_in[1];   // [128,64]
    const float* convw = (const float*)d_in[2];   // [128,64]
    const float* convb = (const float*)d_in[3];   // [128]
    float* out = (float*)d_out;

    const size_t need16 = (size_t)NIMG * 16 * (KCL * CDIM + KCL) * sizeof(float);
    const size_t need8  = (size_t)NIMG * 8  * (KCL * CDIM + KCL) * sizeof(float);

    if (ws_size >= need16) {
        // R12 primary path: 1024 blocks = 4/CU, no launch-bounds squeeze.
        float* vws  = (float*)d_ws;                               // [N][16][K][C]
        float* asws = vws + (size_t)NIMG * 16 * KCL * CDIM;       // [N][16][K]
        netvlad_main<16><<<dim3(NIMG * 16), dim3(256), 0, stream>>>(
            x, convw, convb, vws, asws, 0);
        netvlad_finalize<<<dim3(NIMG * 8), dim3(256), 0, stream>>>(
            vws, asws, cent, out, 16);
    } else if (ws_size >= need8) {
        float* vws  = (float*)d_ws;                               // [N][8][K][C]
        float* asws = vws + (size_t)NIMG * 8 * KCL * CDIM;        // [N][8][K]
        netvlad_main<8><<<dim3(NIMG * 8), dim3(256), 0, stream>>>(
            x, convw, convb, vws, asws, 0);
        netvlad_finalize<<<dim3(NIMG * 8), dim3(256), 0, stream>>>(
            vws, asws, cent, out, 8);
    } else {
        float* vws  = (float*)d_ws;                               // [N][K][C]
        float* asws = vws + (size_t)NIMG * KCL * CDIM;            // [N][K]
        const size_t zb = (size_t)NIMG * (KCL * CDIM + KCL) * sizeof(float);
        hipMemsetAsync(d_ws, 0, zb, stream);
        netvlad_main<8><<<dim3(NIMG * 8), dim3(256), 0, stream>>>(
            x, convw, convb, vws, asws, 1);
        netvlad_finalize<<<dim3(NIMG * 8), dim3(256), 0, stream>>>(
            vws, asws, cent, out, 1);
    }
}

// Round 3
// 127.264 us; speedup vs baseline: 1.4452x; 1.0315x over previous
//
#include <hip/hip_runtime.h>
#include <math.h>

// Problem constants (fixed by the reference setup_inputs)
#define NIMG   64
#define CDIM   64
#define HWPX   4096
#define KCL    128
#define TL     32                // pixels per chunk
#define SHIFT  10.0f             // softmax shift folded into bias
#define RSQRT128 0.08838834764831845f

// LDS strides in shorts (multiples of 8 so b128 stays 16B-aligned)
#define XP_S 72    // xp planes [32 p][64 c]
#define XC_S 40    // xc plane  [64 c][32 p]
#define PH_S 40    // ph plane  [128 k][32 p]

typedef __attribute__((ext_vector_type(8))) short short8; // 8 bf16
typedef __attribute__((ext_vector_type(4))) float f32x4;  // MFMA C/D

#define MFMA(a, b, c) __builtin_amdgcn_mfma_f32_16x16x32_bf16((a), (b), (c), 0, 0, 0)

// Pack the truncated-bf16 prefixes of two floats into one u32 with a single
// v_perm_b32: bytes {f0.b2, f0.b3, f1.b2, f1.b3}. The hi16 of an f32 IS its
// truncated bf16, so no shifts/ors are needed.
#define PERM_HI16 0x07060302u

// ---------------------------------------------------------------------------
// Kernel 1: raw-x planes -> mm1 (W@X, 3-term split) -> in-register softmax
// -> mm2 (P'@X^T, single bf16 planes -- error bounded ~4e-6 on output
// because the VLAD residual is dominated by asum*centroid).
// LESSONS (measured): (256,3)/spill r3+r9; __threadfence 3x r6; 512-thr
// blocks r5.
// R11 (FAILED): launch_bounds(256,4) clamped VGPR 84->64 -> spills, 2.1x.
// R12 (NEUTRAL): NP=16 @ (256,2): 48.0us vs 46.5 -- more resident blocks
// don't help => not latency-hiding-bound. Limit = per-wave serial VALU
// (conversions ~350 ops/chunk/thread, VALUBusy 40% = top pipe).
// R13: VALU-lean conversions, bit-identical numerics:
//   - xp hi/lo: v_perm_b32 packs 2 truncated-bf16 per instr (hi16 of f32
//     == truncated bf16); replaces tsplit + short8 insert packing.
//   - xc / P': v_cvt_pk_bf16_f32 (RNE, same as manual f2bf) via plain asm.
//   Revert to NP=8 (512 blocks): NP=16 cost ~3us extra finalize traffic.
// ---------------------------------------------------------------------------
template <int NP>
__global__ __launch_bounds__(256, 2)
void netvlad_main(const float* __restrict__ x,       // [N][C][HW]
                  const float* __restrict__ conv_w,  // [K][C]
                  const float* __restrict__ conv_b,  // [K]
                  float* __restrict__ vout,          // partials or atomic acc
                  float* __restrict__ asout,
                  int use_atomic)
{
    constexpr int PIXPART = HWPX / NP;   // pixels per block
    constexpr int NCHUNK  = PIXPART / TL;

    __shared__ __align__(16) short xp_hi[TL * XP_S], xp_lo[TL * XP_S]; // 9 KB
    __shared__ __align__(16) short xc[CDIM * XC_S];                    // 5 KB
    __shared__ __align__(16) short ph[KCL * PH_S];                     // 10 KB
    __shared__ float redA[4 * 33];    // ssq partials [wave][p], stride 33
    __shared__ float sumP[4 * TL];    // exp-sum partials [wave][p]

    const int t   = threadIdx.x;
    const int w   = t >> 6;             // wave 0..3
    const int l   = t & 63;
    const int l15 = l & 15, l4 = l >> 4;
    const int n    = blockIdx.x / NP;
    const int part = blockIdx.x - n * NP;
    const int p_s  = t & 31;            // staging pixel
    const int sg   = t >> 5;            // staging c-group (8 c's)

    // ---- W fragments in registers (once): A[m=k][kdim=c], 3-term split ----
    short8 wh[2][2], wl[2][2];
    #pragma unroll
    for (int kt = 0; kt < 2; ++kt) {
        const int krow = (2 * w + kt) * 16 + l15;
        #pragma unroll
        for (int ks = 0; ks < 2; ++ks) {
            const float4* wp = (const float4*)(conv_w + krow * CDIM + ks * 32 + l4 * 8);
            float4 wa = wp[0], wb = wp[1];
            float wv[8] = {wa.x, wa.y, wa.z, wa.w, wb.x, wb.y, wb.z, wb.w};
            #pragma unroll
            for (int j = 0; j < 8; ++j) {
                unsigned u = __builtin_bit_cast(unsigned, wv[j]);
                wh[kt][ks][j] = (short)(u >> 16);
                float hf = __builtin_bit_cast(float, u & 0xffff0000u);
                wl[kt][ks][j] = (short)(__builtin_bit_cast(unsigned, wv[j] - hf) >> 16);
            }
        }
    }
    // bias per D-row (k = (2w+kt)*16 + l4*4 + i), pre-shifted
    float cbr[2][4];
    #pragma unroll
    for (int kt = 0; kt < 2; ++kt)
        #pragma unroll
        for (int i = 0; i < 4; ++i)
            cbr[kt][i] = conv_b[(2 * w + kt) * 16 + l4 * 4 + i] - SHIFT;

    f32x4 acc2[2][4];                   // V tiles [kt][ct]
    #pragma unroll
    for (int a = 0; a < 2; ++a)
        #pragma unroll
        for (int b = 0; b < 4; ++b) acc2[a][b] = (f32x4)0.0f;
    float asr[2][4];                    // asum partials per D-row
    #pragma unroll
    for (int a = 0; a < 2; ++a)
        #pragma unroll
        for (int i = 0; i < 4; ++i) asr[a][i] = 0.f;

    const float* xbase = x + (size_t)n * CDIM * HWPX + part * PIXPART;

    // preload chunk 0
    float xv[8];
    #pragma unroll
    for (int j = 0; j < 8; ++j)
        xv[j] = xbase[(sg * 8 + j) * HWPX + p_s];

    for (int ch = 0; ch < NCHUNK; ++ch) {
        // ---- stage: ssq partial + x planes --------------------------------
        float ssq = 0.f;
        #pragma unroll
        for (int j = 0; j < 8; ++j) ssq += xv[j] * xv[j];
        ssq += __shfl_xor(ssq, 32);              // combine the wave's 2 sg's
        if (l < 32) redA[w * 33 + p_s] = ssq;

        // xp hi/lo planes: truncation split, packed 2-at-a-time via v_perm.
        // Bit-identical to the old tsplit path.
        unsigned uh[4], ul[4];
        #pragma unroll
        for (int jp = 0; jp < 4; ++jp) {
            const unsigned u0 = __builtin_bit_cast(unsigned, xv[2 * jp]);
            const unsigned u1 = __builtin_bit_cast(unsigned, xv[2 * jp + 1]);
            uh[jp] = __builtin_amdgcn_perm(u1, u0, PERM_HI16);
            const float h0 = __builtin_bit_cast(float, u0 & 0xffff0000u);
            const float h1 = __builtin_bit_cast(float, u1 & 0xffff0000u);
            const unsigned lo0 = __builtin_bit_cast(unsigned, xv[2 * jp] - h0);
            const unsigned lo1 = __builtin_bit_cast(unsigned, xv[2 * jp + 1] - h1);
            ul[jp] = __builtin_amdgcn_perm(lo1, lo0, PERM_HI16);
        }
        *(uint4*)&xp_hi[p_s * XP_S + sg * 8] = make_uint4(uh[0], uh[1], uh[2], uh[3]);
        *(uint4*)&xp_lo[p_s * XP_S + sg * 8] = make_uint4(ul[0], ul[1], ul[2], ul[3]);

        // xc plane (RNE bf16): v_cvt_pk_bf16_f32 = 2 conversions/instr.
        #pragma unroll
        for (int jp = 0; jp < 4; ++jp) {
            unsigned pk;
            asm("v_cvt_pk_bf16_f32 %0, %1, %2"
                : "=v"(pk) : "v"(xv[2 * jp]), "v"(xv[2 * jp + 1]));
            xc[(sg * 8 + 2 * jp)     * XC_S + p_s] = (short)pk;
            xc[(sg * 8 + 2 * jp + 1) * XC_S + p_s] = (short)(pk >> 16);
        }
        __syncthreads();                                  // bar 1: stage done

        // prefetch next chunk while mm1/softmax/mm2 run
        if (ch + 1 < NCHUNK) {
            #pragma unroll
            for (int j = 0; j < 8; ++j)
                xv[j] = xbase[(sg * 8 + j) * HWPX + (ch + 1) * TL + p_s];
        }

        // ---- mm1: a1[kt][pt] = W @ Xraw  (3-term split) -------------------
        f32x4 a1[2][2];
        #pragma unroll
        for (int a = 0; a < 2; ++a)
            #pragma unroll
            for (int b = 0; b < 2; ++b) a1[a][b] = (f32x4)0.0f;
        #pragma unroll
        for (int ks = 0; ks < 2; ++ks) {
            #pragma unroll
            for (int pt = 0; pt < 2; ++pt) {
                short8 bh = *(short8*)&xp_hi[(pt * 16 + l15) * XP_S + ks * 32 + l4 * 8];
                short8 bl = *(short8*)&xp_lo[(pt * 16 + l15) * XP_S + ks * 32 + l4 * 8];
                #pragma unroll
                for (int kt = 0; kt < 2; ++kt) {
                    a1[kt][pt] = MFMA(wh[kt][ks], bh, a1[kt][pt]);
                    a1[kt][pt] = MFMA(wh[kt][ks], bl, a1[kt][pt]);
                    a1[kt][pt] = MFMA(wl[kt][ks], bh, a1[kt][pt]);
                }
            }
        }

        // ---- per-column 1/||x||: sum the 4 per-wave ssq partials ----------
        float rn[2];
        #pragma unroll
        for (int pt = 0; pt < 2; ++pt) {
            const int col = pt * 16 + l15;
            float s0 = redA[col] + redA[33 + col];
            float s1 = redA[2 * 33 + col] + redA[3 * 33 + col];
            rn[pt] = 1.0f / fmaxf(sqrtf(s0 + s1), 1e-12f);
        }

        // ---- in-register softmax over k (no max pass; bias pre-shifted) ---
        float e[2][2][4], sp[2] = {0.f, 0.f};
        #pragma unroll
        for (int kt = 0; kt < 2; ++kt)
            #pragma unroll
            for (int pt = 0; pt < 2; ++pt)
                #pragma unroll
                for (int i = 0; i < 4; ++i) {
                    float ev = __expf(fmaf(a1[kt][pt][i], rn[pt], cbr[kt][i]));
                    e[kt][pt][i] = ev;
                    sp[pt] += ev;
                }
        #pragma unroll
        for (int pt = 0; pt < 2; ++pt) {
            sp[pt] += __shfl_xor(sp[pt], 16);
            sp[pt] += __shfl_xor(sp[pt], 32);     // wave-sum over its 32 k's
        }
        if (l4 == 0) {
            sumP[w * TL + l15]      = sp[0];
            sumP[w * TL + 16 + l15] = sp[1];
        }
        __syncthreads();                                  // bar 2: sumP done

        float rden[2], rdn2[2];
        #pragma unroll
        for (int pt = 0; pt < 2; ++pt) {
            const int col = pt * 16 + l15;
            float den = sumP[col] + sumP[TL + col] + sumP[2 * TL + col] + sumP[3 * TL + col];
            rden[pt] = 1.0f / den;
            rdn2[pt] = rden[pt] * rn[pt];          // fold 1/||x|| into P'
        }

        // ---- P' = P * rn -> single bf16 plane (wave's own 32 ph rows) -----
        // cvt_pk packs the (pt=0, pt=1) pair; hi half stored via >>16
        // (compiler folds to ds_write_b16_d16_hi).
        #pragma unroll
        for (int kt = 0; kt < 2; ++kt)
            #pragma unroll
            for (int i = 0; i < 4; ++i) {
                const int row = (2 * w + kt) * 16 + l4 * 4 + i;
                const float e0 = e[kt][0][i], e1 = e[kt][1][i];
                asr[kt][i] = fmaf(e0, rden[0], asr[kt][i]);
                asr[kt][i] = fmaf(e1, rden[1], asr[kt][i]);
                const float p0 = e0 * rdn2[0], p1 = e1 * rdn2[1];
                unsigned pk;
                asm("v_cvt_pk_bf16_f32 %0, %1, %2" : "=v"(pk) : "v"(p0), "v"(p1));
                ph[row * PH_S + l15]      = (short)pk;
                ph[row * PH_S + 16 + l15] = (short)(pk >> 16);
            }
        // no barrier: mm2 reads only the ph rows this wave just wrote
        // (intra-wave LDS ordering is guaranteed).

        // ---- mm2: V[k][c] += P' @ Xraw^T (single-plane bf16) --------------
        {
            short8 xh2[4];
            #pragma unroll
            for (int ct = 0; ct < 4; ++ct)
                xh2[ct] = *(short8*)&xc[(ct * 16 + l15) * XC_S + l4 * 8];
            #pragma unroll
            for (int kt = 0; kt < 2; ++kt) {
                short8 ah = *(short8*)&ph[((2 * w + kt) * 16 + l15) * PH_S + l4 * 8];
                #pragma unroll
                for (int ct = 0; ct < 4; ++ct)
                    acc2[kt][ct] = MFMA(ah, xh2[ct], acc2[kt][ct]);
            }
        }
        __syncthreads();                                  // bar 3: chunk end
    }

    // ---- V write (coalesced: lanes l15 -> consecutive c) ------------------
    float* vg = use_atomic ? vout + (size_t)n * KCL * CDIM
                           : vout + (size_t)blockIdx.x * KCL * CDIM;
    #pragma unroll
    for (int kt = 0; kt < 2; ++kt)
        #pragma unroll
        for (int ct = 0; ct < 4; ++ct)
            #pragma unroll
            for (int i = 0; i < 4; ++i) {
                const int row = (2 * w + kt) * 16 + l4 * 4 + i;
                const int col = ct * 16 + l15;
                if (use_atomic) atomicAdd(&vg[row * CDIM + col], acc2[kt][ct][i]);
                else            vg[row * CDIM + col] = acc2[kt][ct][i];
            }

    // ---- asum: reduce over l15 lanes, lane0-of-16 writes ------------------
    #pragma unroll
    for (int kt = 0; kt < 2; ++kt)
        #pragma unroll
        for (int i = 0; i < 4; ++i) {
            float v = asr[kt][i];
            v += __shfl_xor(v, 1); v += __shfl_xor(v, 2);
            v += __shfl_xor(v, 4); v += __shfl_xor(v, 8);
            if (l15 == 0) {
                const int row = (2 * w + kt) * 16 + l4 * 4 + i;
                if (use_atomic) atomicAdd(&asout[n * KCL + row], v);
                else            asout[blockIdx.x * KCL + row] = v;
            }
        }
}

// ---------------------------------------------------------------------------
// Kernel 2: sum partials; vlad = V - asum*cent; intra-norm; global norm.
// After intra-norm every row has unit L2 norm -> global denom = sqrt(128).
// grid = NIMG*8 blocks x 256 threads; thread -> (k, 4 c's). Fully parallel.
// ---------------------------------------------------------------------------
__global__ __launch_bounds__(256)
void netvlad_finalize(const float* __restrict__ vpart,   // [N][nparts][K][C]
                      const float* __restrict__ aspart,  // [N][nparts][K]
                      const float* __restrict__ cent,    // [K][C]
                      float* __restrict__ out,           // [N][K*C]
                      int nparts)
{
    const int t = threadIdx.x;
    const int n  = blockIdx.x >> 3;
    const int kg = blockIdx.x & 7;
    const int k  = kg * 16 + (t >> 4);
    const int c0 = (t & 15) * 4;

    float vsum[4] = {0.f, 0.f, 0.f, 0.f};
    float av = 0.f;
    for (int pt = 0; pt < nparts; ++pt) {
        const float* vg = vpart + (((size_t)n * nparts + pt) * KCL + k) * CDIM + c0;
        float4 a = *(const float4*)vg;
        vsum[0] += a.x; vsum[1] += a.y; vsum[2] += a.z; vsum[3] += a.w;
        av += aspart[(n * nparts + pt) * KCL + k];
    }

    float4 cq = *(const float4*)(cent + k * CDIM + c0);
    float cc[4] = {cq.x, cq.y, cq.z, cq.w};
    float ss = 0.f;
    #pragma unroll
    for (int j = 0; j < 4; ++j) {
        vsum[j] -= av * cc[j];
        ss += vsum[j] * vsum[j];
    }
    // row sumsq over the 16 lanes covering this k
    ss += __shfl_xor(ss, 1); ss += __shfl_xor(ss, 2);
    ss += __shfl_xor(ss, 4); ss += __shfl_xor(ss, 8);
    const float s = (1.0f / fmaxf(sqrtf(ss), 1e-12f)) * RSQRT128;

    float4 o;
    o.x = vsum[0] * s; o.y = vsum[1] * s; o.z = vsum[2] * s; o.w = vsum[3] * s;
    *(float4*)(out + (size_t)n * KCL * CDIM + k * CDIM + c0) = o;
}

// ---------------------------------------------------------------------------
extern "C" void kernel_launch(void* const* d_in, const int* in_sizes, int n_in,
                              void* d_out, int out_size, void* d_ws, size_t ws_size,
                              hipStream_t stream) {
    const float* x     = (const float*)d_in[0];   // [64,64,64,64]
    const float* cent  = (const float*)d_in[1];   // [128,64]
    const float* convw = (const float*)d_in[2];   // [128,64]
    const float* convb = (const float*)d_in[3];   // [128]
    float* out = (float*)d_out;

    const size_t need8 = (size_t)NIMG * 8 * (KCL * CDIM + KCL) * sizeof(float);

    if (ws_size >= need8) {
        float* vws  = (float*)d_ws;                               // [N][8][K][C]
        float* asws = vws + (size_t)NIMG * 8 * KCL * CDIM;        // [N][8][K]
        netvlad_main<8><<<dim3(NIMG * 8), dim3(256), 0, stream>>>(
            x, convw, convb, vws, asws, 0);
        netvlad_finalize<<<dim3(NIMG * 8), dim3(256), 0, stream>>>(
            vws, asws, cent, out, 8);
    } else {
        float* vws  = (float*)d_ws;                               // [N][K][C]
        float* asws = vws + (size_t)NIMG * KCL * CDIM;            // [N][K]
        const size_t zb = (size_t)NIMG * (KCL * CDIM + KCL) * sizeof(float);
        hipMemsetAsync(d_ws, 0, zb, stream);
        netvlad_main<8><<<dim3(NIMG * 8), dim3(256), 0, stream>>>(
            x, convw, convb, vws, asws, 1);
        netvlad_finalize<<<dim3(NIMG * 8), dim3(256), 0, stream>>>(
            vws, asws, cent, out, 1);
    }
}

// Round 4
// 125.524 us; speedup vs baseline: 1.4652x; 1.0139x over previous
//
#include <hip/hip_runtime.h>
#include <math.h>

// Problem constants (fixed by the reference setup_inputs)
#define NIMG   64
#define CDIM   64
#define HWPX   4096
#define KCL    128
#define TL     32                // pixels per chunk
#define SHIFT  10.0f             // softmax shift folded into bias
#define RSQRT128 0.08838834764831845f

// LDS strides in shorts (multiples of 8 so b128 stays 16B-aligned)
#define XP_S 72    // xp planes [32 p][64 c]
#define XC_S 40    // xc plane  [64 c][32 slot]
#define PH_S 40    // ph plane  [128 k][32 slot]

typedef __attribute__((ext_vector_type(8))) short short8; // 8 bf16
typedef __attribute__((ext_vector_type(4))) float f32x4;  // MFMA C/D

#define MFMA(a, b, c) __builtin_amdgcn_mfma_f32_16x16x32_bf16((a), (b), (c), 0, 0, 0)

// Pack the truncated-bf16 prefixes of two floats into one u32 with a single
// v_perm_b32: bytes {f0.b2, f0.b3, f1.b2, f1.b3}.
#define PERM_HI16 0x07060302u

// ---------------------------------------------------------------------------
// Kernel 1: raw-x planes -> mm1 (W@X, 3-term split) -> in-register softmax
// -> mm2 (P'@X^T, single bf16 planes).
// LESSONS (measured): (256,3)/spill r3+r9; __threadfence 3x r6; 512-thr r5.
// R11 (FAILED): launch_bounds(256,4) -> VGPR 64 -> spills, 2.1x slower.
// R12 (NEUTRAL): NP=16, 4 blocks/CU: 48 vs 46.5us -- extra waves don't help.
// R13 (NEUTRAL): VALU-lean conversions: VALUBusy 37->33% but time flat.
// => Diagnosis: DS-pipe bound (shared per CU: explains R12+R13 nulls).
//    ~64 DS instrs/wave/chunk ~= 480 cyc; x8 waves ~55% of CU cycles.
// R14: cut DS instruction count, bit-identical math:
//   - staging remap: thread = 4 c's x 2 pixels {p, p+16} (pairs in-register)
//   - xc: 8x ds_write_b16 -> 4x b32 (cvt_pk packs the pixel pair)
//   - ph: 16x b16 -> 8x b32 (pt0/pt1 pair); kdim slot = 2*(p&15)+(p>>4)
//     interleave applied to BOTH ph and xc (kdim perm is MFMA-invariant)
//   - redA/sumP: float2 b64 ops (sumP 10 -> 5 instrs)
//   ~64 -> ~48 DS instrs/wave/chunk.
// ---------------------------------------------------------------------------
template <int NP>
__global__ __launch_bounds__(256, 2)
void netvlad_main(const float* __restrict__ x,       // [N][C][HW]
                  const float* __restrict__ conv_w,  // [K][C]
                  const float* __restrict__ conv_b,  // [K]
                  float* __restrict__ vout,          // partials or atomic acc
                  float* __restrict__ asout,
                  int use_atomic)
{
    constexpr int PIXPART = HWPX / NP;   // pixels per block
    constexpr int NCHUNK  = PIXPART / TL;

    __shared__ __align__(16) short xp_hi[TL * XP_S], xp_lo[TL * XP_S]; // 9 KB
    __shared__ __align__(16) short xc[CDIM * XC_S];                    // 5 KB
    __shared__ __align__(16) short ph[KCL * PH_S];                    // 10 KB
    __shared__ __align__(8) float2 redA2[4 * 16];   // ssq pairs [wave][l15]
    __shared__ __align__(8) float2 sumP2[4 * 16];   // exp-sum pairs

    const int t   = threadIdx.x;
    const int w   = t >> 6;             // wave 0..3
    const int l   = t & 63;
    const int l15 = l & 15, l4 = l >> 4;
    const int n    = blockIdx.x / NP;
    const int part = blockIdx.x - n * NP;
    const int cb   = w * 16 + l4 * 4;   // staging c-base (4 c's per thread)

    // ---- W fragments in registers (once): A[m=k][kdim=c], 3-term split ----
    short8 wh[2][2], wl[2][2];
    #pragma unroll
    for (int kt = 0; kt < 2; ++kt) {
        const int krow = (2 * w + kt) * 16 + l15;
        #pragma unroll
        for (int ks = 0; ks < 2; ++ks) {
            const float4* wp = (const float4*)(conv_w + krow * CDIM + ks * 32 + l4 * 8);
            float4 wa = wp[0], wb = wp[1];
            float wv[8] = {wa.x, wa.y, wa.z, wa.w, wb.x, wb.y, wb.z, wb.w};
            #pragma unroll
            for (int j = 0; j < 8; ++j) {
                unsigned u = __builtin_bit_cast(unsigned, wv[j]);
                wh[kt][ks][j] = (short)(u >> 16);
                float hf = __builtin_bit_cast(float, u & 0xffff0000u);
                wl[kt][ks][j] = (short)(__builtin_bit_cast(unsigned, wv[j] - hf) >> 16);
            }
        }
    }
    // bias per D-row (k = (2w+kt)*16 + l4*4 + i), pre-shifted
    float cbr[2][4];
    #pragma unroll
    for (int kt = 0; kt < 2; ++kt)
        #pragma unroll
        for (int i = 0; i < 4; ++i)
            cbr[kt][i] = conv_b[(2 * w + kt) * 16 + l4 * 4 + i] - SHIFT;

    f32x4 acc2[2][4];                   // V tiles [kt][ct]
    #pragma unroll
    for (int a = 0; a < 2; ++a)
        #pragma unroll
        for (int b = 0; b < 4; ++b) acc2[a][b] = (f32x4)0.0f;
    float asr[2][4];                    // asum partials per D-row
    #pragma unroll
    for (int a = 0; a < 2; ++a)
        #pragma unroll
        for (int i = 0; i < 4; ++i) asr[a][i] = 0.f;

    const float* xbase = x + (size_t)n * CDIM * HWPX + part * PIXPART;

    // preload chunk 0: xv[jp*4+jc] = x[cb+jc][p = l15 + jp*16]
    float xv[8];
    #pragma unroll
    for (int jp = 0; jp < 2; ++jp)
        #pragma unroll
        for (int jc = 0; jc < 4; ++jc)
            xv[jp * 4 + jc] = xbase[(cb + jc) * HWPX + l15 + jp * 16];

    for (int ch = 0; ch < NCHUNK; ++ch) {
        // ---- stage: ssq pair + x planes -----------------------------------
        float ssq0 = 0.f, ssq1 = 0.f;
        #pragma unroll
        for (int jc = 0; jc < 4; ++jc) {
            ssq0 += xv[jc] * xv[jc];
            ssq1 += xv[4 + jc] * xv[4 + jc];
        }
        ssq0 += __shfl_xor(ssq0, 16); ssq0 += __shfl_xor(ssq0, 32);
        ssq1 += __shfl_xor(ssq1, 16); ssq1 += __shfl_xor(ssq1, 32);
        if (l < 16) redA2[w * 16 + l15] = make_float2(ssq0, ssq1);

        // xp hi/lo planes: truncation split, b64 per pixel (4 c's)
        #pragma unroll
        for (int jp = 0; jp < 2; ++jp) {
            const int p = l15 + jp * 16;
            const unsigned u0 = __builtin_bit_cast(unsigned, xv[jp * 4 + 0]);
            const unsigned u1 = __builtin_bit_cast(unsigned, xv[jp * 4 + 1]);
            const unsigned u2 = __builtin_bit_cast(unsigned, xv[jp * 4 + 2]);
            const unsigned u3 = __builtin_bit_cast(unsigned, xv[jp * 4 + 3]);
            const unsigned uh01 = __builtin_amdgcn_perm(u1, u0, PERM_HI16);
            const unsigned uh23 = __builtin_amdgcn_perm(u3, u2, PERM_HI16);
            *(uint2*)&xp_hi[p * XP_S + cb] = make_uint2(uh01, uh23);
            const float h0 = __builtin_bit_cast(float, u0 & 0xffff0000u);
            const float h1 = __builtin_bit_cast(float, u1 & 0xffff0000u);
            const float h2 = __builtin_bit_cast(float, u2 & 0xffff0000u);
            const float h3 = __builtin_bit_cast(float, u3 & 0xffff0000u);
            const unsigned lo0 = __builtin_bit_cast(unsigned, xv[jp * 4 + 0] - h0);
            const unsigned lo1 = __builtin_bit_cast(unsigned, xv[jp * 4 + 1] - h1);
            const unsigned lo2 = __builtin_bit_cast(unsigned, xv[jp * 4 + 2] - h2);
            const unsigned lo3 = __builtin_bit_cast(unsigned, xv[jp * 4 + 3] - h3);
            const unsigned ul01 = __builtin_amdgcn_perm(lo1, lo0, PERM_HI16);
            const unsigned ul23 = __builtin_amdgcn_perm(lo3, lo2, PERM_HI16);
            *(uint2*)&xp_lo[p * XP_S + cb] = make_uint2(ul01, ul23);
        }

        // xc plane (RNE bf16): slot s = 2*(p&15) + (p>>4); pixel pair packed
        // into one b32 per c (cvt_pk: lo16 = pixel l15, hi16 = pixel l15+16).
        #pragma unroll
        for (int jc = 0; jc < 4; ++jc) {
            unsigned pk;
            asm("v_cvt_pk_bf16_f32 %0, %1, %2"
                : "=v"(pk) : "v"(xv[jc]), "v"(xv[4 + jc]));
            *(unsigned*)&xc[(cb + jc) * XC_S + 2 * l15] = pk;
        }
        __syncthreads();                                  // bar 1: stage done

        // prefetch next chunk while mm1/softmax/mm2 run
        if (ch + 1 < NCHUNK) {
            #pragma unroll
            for (int jp = 0; jp < 2; ++jp)
                #pragma unroll
                for (int jc = 0; jc < 4; ++jc)
                    xv[jp * 4 + jc] = xbase[(cb + jc) * HWPX + (ch + 1) * TL + l15 + jp * 16];
        }

        // ---- mm1: a1[kt][pt] = W @ Xraw  (3-term split) -------------------
        f32x4 a1[2][2];
        #pragma unroll
        for (int a = 0; a < 2; ++a)
            #pragma unroll
            for (int b = 0; b < 2; ++b) a1[a][b] = (f32x4)0.0f;
        #pragma unroll
        for (int ks = 0; ks < 2; ++ks) {
            #pragma unroll
            for (int pt = 0; pt < 2; ++pt) {
                short8 bh = *(short8*)&xp_hi[(pt * 16 + l15) * XP_S + ks * 32 + l4 * 8];
                short8 bl = *(short8*)&xp_lo[(pt * 16 + l15) * XP_S + ks * 32 + l4 * 8];
                #pragma unroll
                for (int kt = 0; kt < 2; ++kt) {
                    a1[kt][pt] = MFMA(wh[kt][ks], bh, a1[kt][pt]);
                    a1[kt][pt] = MFMA(wh[kt][ks], bl, a1[kt][pt]);
                    a1[kt][pt] = MFMA(wl[kt][ks], bh, a1[kt][pt]);
                }
            }
        }

        // ---- per-column 1/||x||: 4 b64 reads (broadcast over l4/w) --------
        float2 ra0 = redA2[l15],      ra1 = redA2[16 + l15];
        float2 ra2 = redA2[32 + l15], ra3 = redA2[48 + l15];
        float rn[2];
        rn[0] = 1.0f / fmaxf(sqrtf((ra0.x + ra1.x) + (ra2.x + ra3.x)), 1e-12f);
        rn[1] = 1.0f / fmaxf(sqrtf((ra0.y + ra1.y) + (ra2.y + ra3.y)), 1e-12f);

        // ---- in-register softmax over k (no max pass; bias pre-shifted) ---
        float e[2][2][4], sp[2] = {0.f, 0.f};
        #pragma unroll
        for (int kt = 0; kt < 2; ++kt)
            #pragma unroll
            for (int pt = 0; pt < 2; ++pt)
                #pragma unroll
                for (int i = 0; i < 4; ++i) {
                    float ev = __expf(fmaf(a1[kt][pt][i], rn[pt], cbr[kt][i]));
                    e[kt][pt][i] = ev;
                    sp[pt] += ev;
                }
        #pragma unroll
        for (int pt = 0; pt < 2; ++pt) {
            sp[pt] += __shfl_xor(sp[pt], 16);
            sp[pt] += __shfl_xor(sp[pt], 32);     // wave-sum over its 32 k's
        }
        if (l < 16) sumP2[w * 16 + l15] = make_float2(sp[0], sp[1]);
        __syncthreads();                                  // bar 2: sumP done

        float2 q0 = sumP2[l15],      q1 = sumP2[16 + l15];
        float2 q2 = sumP2[32 + l15], q3 = sumP2[48 + l15];
        float rden[2], rdn2[2];
        rden[0] = 1.0f / ((q0.x + q1.x) + (q2.x + q3.x));
        rden[1] = 1.0f / ((q0.y + q1.y) + (q2.y + q3.y));
        rdn2[0] = rden[0] * rn[0];
        rdn2[1] = rden[1] * rn[1];

        // ---- P' -> ph: one b32 per (kt,i) packs the pt0/pt1 pair ----------
        #pragma unroll
        for (int kt = 0; kt < 2; ++kt)
            #pragma unroll
            for (int i = 0; i < 4; ++i) {
                const int row = (2 * w + kt) * 16 + l4 * 4 + i;
                const float e0 = e[kt][0][i], e1 = e[kt][1][i];
                asr[kt][i] = fmaf(e0, rden[0], asr[kt][i]);
                asr[kt][i] = fmaf(e1, rden[1], asr[kt][i]);
                const float p0 = e0 * rdn2[0], p1 = e1 * rdn2[1];
                unsigned pk;
                asm("v_cvt_pk_bf16_f32 %0, %1, %2" : "=v"(pk) : "v"(p0), "v"(p1));
                *(unsigned*)&ph[row * PH_S + 2 * l15] = pk;
            }
        // no barrier: mm2 reads only the ph rows this wave just wrote.

        // ---- mm2: V[k][c] += P' @ Xraw^T (kdim = interleaved pixel slots) -
        {
            short8 xh2[4];
            #pragma unroll
            for (int ct = 0; ct < 4; ++ct)
                xh2[ct] = *(short8*)&xc[(ct * 16 + l15) * XC_S + l4 * 8];
            #pragma unroll
            for (int kt = 0; kt < 2; ++kt) {
                short8 ah = *(short8*)&ph[((2 * w + kt) * 16 + l15) * PH_S + l4 * 8];
                #pragma unroll
                for (int ct = 0; ct < 4; ++ct)
                    acc2[kt][ct] = MFMA(ah, xh2[ct], acc2[kt][ct]);
            }
        }
        __syncthreads();                                  // bar 3: chunk end
    }

    // ---- V write (coalesced: lanes l15 -> consecutive c) ------------------
    float* vg = use_atomic ? vout + (size_t)n * KCL * CDIM
                           : vout + (size_t)blockIdx.x * KCL * CDIM;
    #pragma unroll
    for (int kt = 0; kt < 2; ++kt)
        #pragma unroll
        for (int ct = 0; ct < 4; ++ct)
            #pragma unroll
            for (int i = 0; i < 4; ++i) {
                const int row = (2 * w + kt) * 16 + l4 * 4 + i;
                const int col = ct * 16 + l15;
                if (use_atomic) atomicAdd(&vg[row * CDIM + col], acc2[kt][ct][i]);
                else            vg[row * CDIM + col] = acc2[kt][ct][i];
            }

    // ---- asum: reduce over l15 lanes, lane0-of-16 writes ------------------
    #pragma unroll
    for (int kt = 0; kt < 2; ++kt)
        #pragma unroll
        for (int i = 0; i < 4; ++i) {
            float v = asr[kt][i];
            v += __shfl_xor(v, 1); v += __shfl_xor(v, 2);
            v += __shfl_xor(v, 4); v += __shfl_xor(v, 8);
            if (l15 == 0) {
                const int row = (2 * w + kt) * 16 + l4 * 4 + i;
                if (use_atomic) atomicAdd(&asout[n * KCL + row], v);
                else            asout[blockIdx.x * KCL + row] = v;
            }
        }
}

// ---------------------------------------------------------------------------
// Kernel 2: sum partials; vlad = V - asum*cent; intra-norm; global norm.
// ---------------------------------------------------------------------------
__global__ __launch_bounds__(256)
void netvlad_finalize(const float* __restrict__ vpart,   // [N][nparts][K][C]
                      const float* __restrict__ aspart,  // [N][nparts][K]
                      const float* __restrict__ cent,    // [K][C]
                      float* __restrict__ out,           // [N][K*C]
                      int nparts)
{
    const int t = threadIdx.x;
    const int n  = blockIdx.x >> 3;
    const int kg = blockIdx.x & 7;
    const int k  = kg * 16 + (t >> 4);
    const int c0 = (t & 15) * 4;

    float vsum[4] = {0.f, 0.f, 0.f, 0.f};
    float av = 0.f;
    for (int pt = 0; pt < nparts; ++pt) {
        const float* vg = vpart + (((size_t)n * nparts + pt) * KCL + k) * CDIM + c0;
        float4 a = *(const float4*)vg;
        vsum[0] += a.x; vsum[1] += a.y; vsum[2] += a.z; vsum[3] += a.w;
        av += aspart[(n * nparts + pt) * KCL + k];
    }

    float4 cq = *(const float4*)(cent + k * CDIM + c0);
    float cc[4] = {cq.x, cq.y, cq.z, cq.w};
    float ss = 0.f;
    #pragma unroll
    for (int j = 0; j < 4; ++j) {
        vsum[j] -= av * cc[j];
        ss += vsum[j] * vsum[j];
    }
    // row sumsq over the 16 lanes covering this k
    ss += __shfl_xor(ss, 1); ss += __shfl_xor(ss, 2);
    ss += __shfl_xor(ss, 4); ss += __shfl_xor(ss, 8);
    const float s = (1.0f / fmaxf(sqrtf(ss), 1e-12f)) * RSQRT128;

    float4 o;
    o.x = vsum[0] * s; o.y = vsum[1] * s; o.z = vsum[2] * s; o.w = vsum[3] * s;
    *(float4*)(out + (size_t)n * KCL * CDIM + k * CDIM + c0) = o;
}

// ---------------------------------------------------------------------------
extern "C" void kernel_launch(void* const* d_in, const int* in_sizes, int n_in,
                              void* d_out, int out_size, void* d_ws, size_t ws_size,
                              hipStream_t stream) {
    const float* x     = (const float*)d_in[0];   // [64,64,64,64]
    const float* cent  = (const float*)d_in[1];   // [128,64]
    const float* convw = (const float*)d_in[2];   // [128,64]
    const float* convb = (const float*)d_in[3];   // [128]
    float* out = (float*)d_out;

    const size_t need8 = (size_t)NIMG * 8 * (KCL * CDIM + KCL) * sizeof(float);

    if (ws_size >= need8) {
        float* vws  = (float*)d_ws;                               // [N][8][K][C]
        float* asws = vws + (size_t)NIMG * 8 * KCL * CDIM;        // [N][8][K]
        netvlad_main<8><<<dim3(NIMG * 8), dim3(256), 0, stream>>>(
            x, convw, convb, vws, asws, 0);
        netvlad_finalize<<<dim3(NIMG * 8), dim3(256), 0, stream>>>(
            vws, asws, cent, out, 8);
    } else {
        float* vws  = (float*)d_ws;                               // [N][K][C]
        float* asws = vws + (size_t)NIMG * KCL * CDIM;            // [N][K]
        const size_t zb = (size_t)NIMG * (KCL * CDIM + KCL) * sizeof(float);
        hipMemsetAsync(d_ws, 0, zb, stream);
        netvlad_main<8><<<dim3(NIMG * 8), dim3(256), 0, stream>>>(
            x, convw, convb, vws, asws, 1);
        netvlad_finalize<<<dim3(NIMG * 8), dim3(256), 0, stream>>>(
            vws, asws, cent, out, 1);
    }
}

// Round 5
// 124.831 us; speedup vs baseline: 1.4733x; 1.0056x over previous
//
#include <hip/hip_runtime.h>
#include <math.h>

// Problem constants (fixed by the reference setup_inputs)
#define NIMG   64
#define CDIM   64
#define HWPX   4096
#define KCL    128
#define TL     32                // pixels per chunk
#define SHIFT  10.0f             // softmax shift folded into bias
#define RSQRT128 0.08838834764831845f

// LDS strides in shorts (multiples of 8 so b128 stays 16B-aligned)
#define XP_S 72    // xp planes [32 p][64 c]
#define XC_S 40    // xc plane  [64 c][32 p]
#define PH_S 40    // ph plane  [128 k][32 p]

typedef __attribute__((ext_vector_type(8))) short short8; // 8 bf16
typedef __attribute__((ext_vector_type(4))) float f32x4;  // MFMA C/D

#define MFMA(a, b, c) __builtin_amdgcn_mfma_f32_16x16x32_bf16((a), (b), (c), 0, 0, 0)

// Pack the truncated-bf16 prefixes of two floats into one u32 with a single
// v_perm_b32: bytes {f0.b2, f0.b3, f1.b2, f1.b3}.
#define PERM_HI16 0x07060302u

// ---------------------------------------------------------------------------
// Kernel 1: raw-x planes -> mm1 (W@X, 3-term split) -> in-register softmax
// -> mm2 (P'@X^T, single bf16 planes).
// LESSONS (measured): (256,3)/spill r3+r9; __threadfence 3x r6; 512-thr r5.
// R11 (FAILED): launch_bounds(256,4) -> VGPR 64 -> spills, 2.1x slower.
// R12 (NEUTRAL): NP=16, 4 blocks/CU: extra waves don't help.
// R13 (NEUTRAL): VALU-lean conversions: VALUBusy 37->33% but time flat.
// R14 (REGRESSED 51us): DS-instr cut via staging remap -- worse conflicts
//   (+0.5M), 64B load segments, extra shfls(=DS). Reverted its layout.
// => Diagnosis: no pipe is binding (Mfma 13, VALU 33, HBM 14, DS ~55%-ish
//    upper bound but cuts don't help). Limiter = serial barrier-to-barrier
//    dependency chain: 3 full-drain barriers x 16 chunks with only 2
//    blocks/CU to cover the drains.
// R15: double-buffer the stage planes (xp/xc/redA); stage(ch+1) overlaps
//   mm1/softmax/mm2(ch); 3 -> 2 barriers per chunk. Layout = R13's
//   (best measured). LDS 25.6 -> 39.5 KB (still fine at 2 blocks/CU).
// ---------------------------------------------------------------------------
template <int NP>
__global__ __launch_bounds__(256, 2)
void netvlad_main(const float* __restrict__ x,       // [N][C][HW]
                  const float* __restrict__ conv_w,  // [K][C]
                  const float* __restrict__ conv_b,  // [K]
                  float* __restrict__ vout,          // partials or atomic acc
                  float* __restrict__ asout,
                  int use_atomic)
{
    constexpr int PIXPART = HWPX / NP;   // pixels per block
    constexpr int NCHUNK  = PIXPART / TL;

    __shared__ __align__(16) short xp_hi[2][TL * XP_S], xp_lo[2][TL * XP_S]; // 18 KB
    __shared__ __align__(16) short xc[2][CDIM * XC_S];                       // 10 KB
    __shared__ __align__(16) short ph[KCL * PH_S];                           // 10 KB
    __shared__ float redA[2][4 * 33];   // ssq partials [buf][wave][p]
    __shared__ float sumP[4 * TL];      // exp-sum partials [wave][p]

    const int t   = threadIdx.x;
    const int w   = t >> 6;             // wave 0..3
    const int l   = t & 63;
    const int l15 = l & 15, l4 = l >> 4;
    const int n    = blockIdx.x / NP;
    const int part = blockIdx.x - n * NP;
    const int p_s  = t & 31;            // staging pixel
    const int sg   = t >> 5;            // staging c-group (8 c's)

    // ---- W fragments in registers (once): A[m=k][kdim=c], 3-term split ----
    short8 wh[2][2], wl[2][2];
    #pragma unroll
    for (int kt = 0; kt < 2; ++kt) {
        const int krow = (2 * w + kt) * 16 + l15;
        #pragma unroll
        for (int ks = 0; ks < 2; ++ks) {
            const float4* wp = (const float4*)(conv_w + krow * CDIM + ks * 32 + l4 * 8);
            float4 wa = wp[0], wb = wp[1];
            float wv[8] = {wa.x, wa.y, wa.z, wa.w, wb.x, wb.y, wb.z, wb.w};
            #pragma unroll
            for (int j = 0; j < 8; ++j) {
                unsigned u = __builtin_bit_cast(unsigned, wv[j]);
                wh[kt][ks][j] = (short)(u >> 16);
                float hf = __builtin_bit_cast(float, u & 0xffff0000u);
                wl[kt][ks][j] = (short)(__builtin_bit_cast(unsigned, wv[j] - hf) >> 16);
            }
        }
    }
    // bias per D-row (k = (2w+kt)*16 + l4*4 + i), pre-shifted
    float cbr[2][4];
    #pragma unroll
    for (int kt = 0; kt < 2; ++kt)
        #pragma unroll
        for (int i = 0; i < 4; ++i)
            cbr[kt][i] = conv_b[(2 * w + kt) * 16 + l4 * 4 + i] - SHIFT;

    f32x4 acc2[2][4];                   // V tiles [kt][ct]
    #pragma unroll
    for (int a = 0; a < 2; ++a)
        #pragma unroll
        for (int b = 0; b < 4; ++b) acc2[a][b] = (f32x4)0.0f;
    float asr[2][4];                    // asum partials per D-row
    #pragma unroll
    for (int a = 0; a < 2; ++a)
        #pragma unroll
        for (int i = 0; i < 4; ++i) asr[a][i] = 0.f;

    const float* xbase = x + (size_t)n * CDIM * HWPX + part * PIXPART;

    float xv[8];

    // stage: ssq partial + xp hi/lo planes + xc plane into buffer `buf`.
    auto stage = [&](int buf) {
        float ssq = 0.f;
        #pragma unroll
        for (int j = 0; j < 8; ++j) ssq += xv[j] * xv[j];
        ssq += __shfl_xor(ssq, 32);              // combine the wave's 2 sg's
        if (l < 32) redA[buf][w * 33 + p_s] = ssq;

        unsigned uh[4], ul[4];
        #pragma unroll
        for (int jp = 0; jp < 4; ++jp) {
            const unsigned u0 = __builtin_bit_cast(unsigned, xv[2 * jp]);
            const unsigned u1 = __builtin_bit_cast(unsigned, xv[2 * jp + 1]);
            uh[jp] = __builtin_amdgcn_perm(u1, u0, PERM_HI16);
            const float h0 = __builtin_bit_cast(float, u0 & 0xffff0000u);
            const float h1 = __builtin_bit_cast(float, u1 & 0xffff0000u);
            const unsigned lo0 = __builtin_bit_cast(unsigned, xv[2 * jp] - h0);
            const unsigned lo1 = __builtin_bit_cast(unsigned, xv[2 * jp + 1] - h1);
            ul[jp] = __builtin_amdgcn_perm(lo1, lo0, PERM_HI16);
        }
        *(uint4*)&xp_hi[buf][p_s * XP_S + sg * 8] = make_uint4(uh[0], uh[1], uh[2], uh[3]);
        *(uint4*)&xp_lo[buf][p_s * XP_S + sg * 8] = make_uint4(ul[0], ul[1], ul[2], ul[3]);

        #pragma unroll
        for (int jp = 0; jp < 4; ++jp) {
            unsigned pk;
            asm("v_cvt_pk_bf16_f32 %0, %1, %2"
                : "=v"(pk) : "v"(xv[2 * jp]), "v"(xv[2 * jp + 1]));
            xc[buf][(sg * 8 + 2 * jp)     * XC_S + p_s] = (short)pk;
            xc[buf][(sg * 8 + 2 * jp + 1) * XC_S + p_s] = (short)(pk >> 16);
        }
    };

    // ---- prologue: stage chunk 0, prefetch chunk 1 ------------------------
    #pragma unroll
    for (int j = 0; j < 8; ++j)
        xv[j] = xbase[(sg * 8 + j) * HWPX + p_s];
    stage(0);
    if (NCHUNK > 1) {
        #pragma unroll
        for (int j = 0; j < 8; ++j)
            xv[j] = xbase[(sg * 8 + j) * HWPX + TL + p_s];
    }
    __syncthreads();

    for (int ch = 0; ch < NCHUNK; ++ch) {
        const int cur = ch & 1;

        // ---- stage next chunk into the other buffer (overlaps compute) ---
        if (ch + 1 < NCHUNK) {
            stage(cur ^ 1);
            if (ch + 2 < NCHUNK) {
                #pragma unroll
                for (int j = 0; j < 8; ++j)
                    xv[j] = xbase[(sg * 8 + j) * HWPX + (ch + 2) * TL + p_s];
            }
        }

        // ---- mm1: a1[kt][pt] = W @ Xraw  (3-term split) -------------------
        f32x4 a1[2][2];
        #pragma unroll
        for (int a = 0; a < 2; ++a)
            #pragma unroll
            for (int b = 0; b < 2; ++b) a1[a][b] = (f32x4)0.0f;
        #pragma unroll
        for (int ks = 0; ks < 2; ++ks) {
            #pragma unroll
            for (int pt = 0; pt < 2; ++pt) {
                short8 bh = *(short8*)&xp_hi[cur][(pt * 16 + l15) * XP_S + ks * 32 + l4 * 8];
                short8 bl = *(short8*)&xp_lo[cur][(pt * 16 + l15) * XP_S + ks * 32 + l4 * 8];
                #pragma unroll
                for (int kt = 0; kt < 2; ++kt) {
                    a1[kt][pt] = MFMA(wh[kt][ks], bh, a1[kt][pt]);
                    a1[kt][pt] = MFMA(wh[kt][ks], bl, a1[kt][pt]);
                    a1[kt][pt] = MFMA(wl[kt][ks], bh, a1[kt][pt]);
                }
            }
        }

        // ---- per-column 1/||x||: sum the 4 per-wave ssq partials ----------
        float rn[2];
        #pragma unroll
        for (int pt = 0; pt < 2; ++pt) {
            const int col = pt * 16 + l15;
            float s0 = redA[cur][col] + redA[cur][33 + col];
            float s1 = redA[cur][2 * 33 + col] + redA[cur][3 * 33 + col];
            rn[pt] = 1.0f / fmaxf(sqrtf(s0 + s1), 1e-12f);
        }

        // ---- in-register softmax over k (no max pass; bias pre-shifted) ---
        float e[2][2][4], sp[2] = {0.f, 0.f};
        #pragma unroll
        for (int kt = 0; kt < 2; ++kt)
            #pragma unroll
            for (int pt = 0; pt < 2; ++pt)
                #pragma unroll
                for (int i = 0; i < 4; ++i) {
                    float ev = __expf(fmaf(a1[kt][pt][i], rn[pt], cbr[kt][i]));
                    e[kt][pt][i] = ev;
                    sp[pt] += ev;
                }
        #pragma unroll
        for (int pt = 0; pt < 2; ++pt) {
            sp[pt] += __shfl_xor(sp[pt], 16);
            sp[pt] += __shfl_xor(sp[pt], 32);     // wave-sum over its 32 k's
        }
        if (l4 == 0) {
            sumP[w * TL + l15]      = sp[0];
            sumP[w * TL + 16 + l15] = sp[1];
        }
        __syncthreads();                                  // bar 1: sumP done

        float rden[2], rdn2[2];
        #pragma unroll
        for (int pt = 0; pt < 2; ++pt) {
            const int col = pt * 16 + l15;
            float den = sumP[col] + sumP[TL + col] + sumP[2 * TL + col] + sumP[3 * TL + col];
            rden[pt] = 1.0f / den;
            rdn2[pt] = rden[pt] * rn[pt];          // fold 1/||x|| into P'
        }

        // ---- P' = P * rn -> single bf16 plane (wave's own 32 ph rows) -----
        #pragma unroll
        for (int kt = 0; kt < 2; ++kt)
            #pragma unroll
            for (int i = 0; i < 4; ++i) {
                const int row = (2 * w + kt) * 16 + l4 * 4 + i;
                const float e0 = e[kt][0][i], e1 = e[kt][1][i];
                asr[kt][i] = fmaf(e0, rden[0], asr[kt][i]);
                asr[kt][i] = fmaf(e1, rden[1], asr[kt][i]);
                const float p0 = e0 * rdn2[0], p1 = e1 * rdn2[1];
                unsigned pk;
                asm("v_cvt_pk_bf16_f32 %0, %1, %2" : "=v"(pk) : "v"(p0), "v"(p1));
                ph[row * PH_S + l15]      = (short)pk;
                ph[row * PH_S + 16 + l15] = (short)(pk >> 16);
            }
        // no barrier: mm2 reads only the ph rows this wave just wrote
        // (intra-wave LDS ordering is guaranteed).

        // ---- mm2: V[k][c] += P' @ Xraw^T (single-plane bf16) --------------
        {
            short8 xh2[4];
            #pragma unroll
            for (int ct = 0; ct < 4; ++ct)
                xh2[ct] = *(short8*)&xc[cur][(ct * 16 + l15) * XC_S + l4 * 8];
            #pragma unroll
            for (int kt = 0; kt < 2; ++kt) {
                short8 ah = *(short8*)&ph[((2 * w + kt) * 16 + l15) * PH_S + l4 * 8];
                #pragma unroll
                for (int ct = 0; ct < 4; ++ct)
                    acc2[kt][ct] = MFMA(ah, xh2[ct], acc2[kt][ct]);
            }
        }
        __syncthreads();   // bar 2: chunk end (protects buf[cur] for restage,
                           // sumP for next write, ph for next write)
    }

    // ---- V write (coalesced: lanes l15 -> consecutive c) ------------------
    float* vg = use_atomic ? vout + (size_t)n * KCL * CDIM
                           : vout + (size_t)blockIdx.x * KCL * CDIM;
    #pragma unroll
    for (int kt = 0; kt < 2; ++kt)
        #pragma unroll
        for (int ct = 0; ct < 4; ++ct)
            #pragma unroll
            for (int i = 0; i < 4; ++i) {
                const int row = (2 * w + kt) * 16 + l4 * 4 + i;
                const int col = ct * 16 + l15;
                if (use_atomic) atomicAdd(&vg[row * CDIM + col], acc2[kt][ct][i]);
                else            vg[row * CDIM + col] = acc2[kt][ct][i];
            }

    // ---- asum: reduce over l15 lanes, lane0-of-16 writes ------------------
    #pragma unroll
    for (int kt = 0; kt < 2; ++kt)
        #pragma unroll
        for (int i = 0; i < 4; ++i) {
            float v = asr[kt][i];
            v += __shfl_xor(v, 1); v += __shfl_xor(v, 2);
            v += __shfl_xor(v, 4); v += __shfl_xor(v, 8);
            if (l15 == 0) {
                const int row = (2 * w + kt) * 16 + l4 * 4 + i;
                if (use_atomic) atomicAdd(&asout[n * KCL + row], v);
                else            asout[blockIdx.x * KCL + row] = v;
            }
        }
}

// ---------------------------------------------------------------------------
// Kernel 2: sum partials; vlad = V - asum*cent; intra-norm; global norm.
// ---------------------------------------------------------------------------
__global__ __launch_bounds__(256)
void netvlad_finalize(const float* __restrict__ vpart,   // [N][nparts][K][C]
                      const float* __restrict__ aspart,  // [N][nparts][K]
                      const float* __restrict__ cent,    // [K][C]
                      float* __restrict__ out,           // [N][K*C]
                      int nparts)
{
    const int t = threadIdx.x;
    const int n  = blockIdx.x >> 3;
    const int kg = blockIdx.x & 7;
    const int k  = kg * 16 + (t >> 4);
    const int c0 = (t & 15) * 4;

    float vsum[4] = {0.f, 0.f, 0.f, 0.f};
    float av = 0.f;
    for (int pt = 0; pt < nparts; ++pt) {
        const float* vg = vpart + (((size_t)n * nparts + pt) * KCL + k) * CDIM + c0;
        float4 a = *(const float4*)vg;
        vsum[0] += a.x; vsum[1] += a.y; vsum[2] += a.z; vsum[3] += a.w;
        av += aspart[(n * nparts + pt) * KCL + k];
    }

    float4 cq = *(const float4*)(cent + k * CDIM + c0);
    float cc[4] = {cq.x, cq.y, cq.z, cq.w};
    float ss = 0.f;
    #pragma unroll
    for (int j = 0; j < 4; ++j) {
        vsum[j] -= av * cc[j];
        ss += vsum[j] * vsum[j];
    }
    // row sumsq over the 16 lanes covering this k
    ss += __shfl_xor(ss, 1); ss += __shfl_xor(ss, 2);
    ss += __shfl_xor(ss, 4); ss += __shfl_xor(ss, 8);
    const float s = (1.0f / fmaxf(sqrtf(ss), 1e-12f)) * RSQRT128;

    float4 o;
    o.x = vsum[0] * s; o.y = vsum[1] * s; o.z = vsum[2] * s; o.w = vsum[3] * s;
    *(float4*)(out + (size_t)n * KCL * CDIM + k * CDIM + c0) = o;
}

// ---------------------------------------------------------------------------
extern "C" void kernel_launch(void* const* d_in, const int* in_sizes, int n_in,
                              void* d_out, int out_size, void* d_ws, size_t ws_size,
                              hipStream_t stream) {
    const float* x     = (const float*)d_in[0];   // [64,64,64,64]
    const float* cent  = (const float*)d_in[1];   // [128,64]
    const float* convw = (const float*)d_in[2];   // [128,64]
    const float* convb = (const float*)d_in[3];   // [128]
    float* out = (float*)d_out;

    const size_t need8 = (size_t)NIMG * 8 * (KCL * CDIM + KCL) * sizeof(float);

    if (ws_size >= need8) {
        float* vws  = (float*)d_ws;                               // [N][8][K][C]
        float* asws = vws + (size_t)NIMG * 8 * KCL * CDIM;        // [N][8][K]
        netvlad_main<8><<<dim3(NIMG * 8), dim3(256), 0, stream>>>(
            x, convw, convb, vws, asws, 0);
        netvlad_finalize<<<dim3(NIMG * 8), dim3(256), 0, stream>>>(
            vws, asws, cent, out, 8);
    } else {
        float* vws  = (float*)d_ws;                               // [N][K][C]
        float* asws = vws + (size_t)NIMG * KCL * CDIM;            // [N][K]
        const size_t zb = (size_t)NIMG * (KCL * CDIM + KCL) * sizeof(float);
        hipMemsetAsync(d_ws, 0, zb, stream);
        netvlad_main<8><<<dim3(NIMG * 8), dim3(256), 0, stream>>>(
            x, convw, convb, vws, asws, 1);
        netvlad_finalize<<<dim3(NIMG * 8), dim3(256), 0, stream>>>(
            vws, asws, cent, out, 1);
    }
}